// Round 2
// baseline (2072.859 us; speedup 1.0000x reference)
//
#include <hip/hip_runtime.h>
#include <math.h>

// ---------- bf16 helpers ----------
__device__ __forceinline__ float bf2f(unsigned short u) {
    union { unsigned int i; float f; } c;
    c.i = ((unsigned int)u) << 16;
    return c.f;
}
__device__ __forceinline__ unsigned short f2bf(float f) {
    union { float f; unsigned int i; } c;
    c.f = f;
    unsigned int b = c.i + 0x7FFFu + ((c.i >> 16) & 1u);  // round-nearest-even
    return (unsigned short)(b >> 16);
}
__device__ __forceinline__ float eluf(float v) {   // jax.nn.elu, alpha=1
    return v > 0.f ? v : (expf(v) - 1.f);
}
__device__ __forceinline__ float lrelu(float v) {  // leaky_relu slope 0.2
    return v >= 0.f ? v : 0.2f * v;
}

// ---------- 0. input dtype detection: 1 = bf16, 0 = f32 ----------
// If h_x is bf16, the LOW halfword of each 32-bit word is a sane N(0,1) bf16
// (biased exponent in [114,136] w.p. ~0.999). If h_x is f32, that halfword is
// raw low mantissa bits -> exponent field uniform (P(sane) ~ 0.09).
__global__ void detect_kernel(const unsigned int* __restrict__ w, int nwords,
                              int* __restrict__ flag)
{
    __shared__ int cnt_s;
    if (threadIdx.x == 0) cnt_s = 0;
    __syncthreads();
    int sane = 0;
    for (int i = threadIdx.x; i < nwords; i += 256) {
        unsigned int lo = w[i] & 0xffffu;
        int e = (int)((lo >> 7) & 0xffu);
        if (e >= 114 && e <= 136) sane++;
    }
    atomicAdd(&cnt_s, sane);
    __syncthreads();
    if (threadIdx.x == 0) *flag = (2 * cnt_s > nwords) ? 1 : 0;
}

// ---------- 1. fused elu + GEMM: P[y] = elu(x_y) @ [Wsrc | Wdst]  ([N,128] f32) ----------
__global__ __launch_bounds__(256) void gemm_elu_kernel(
    const void* __restrict__ xh, const void* __restrict__ xt,
    const void* __restrict__ Wsrc, const void* __restrict__ Wdst,
    const int* __restrict__ flag,
    float* __restrict__ P, int N, int D)
{
    __shared__ float xs[64][33];    // 64 rows x 32 k, +1 pad
    __shared__ float wt[32][128];   // 32 k x 128 cols
    const int isbf = *flag;
    const void* xv = (blockIdx.y == 0) ? xh : xt;
    float* Pout = P + (size_t)blockIdx.y * (size_t)N * 128u;
    const int rowBase = blockIdx.x * 64;
    const int tid = threadIdx.x;
    const int tcx = tid & 15;   // col group: cols tcx*8 .. +7
    const int tcy = tid >> 4;   // row group: rows tcy*4 .. +3

    float acc[4][8];
#pragma unroll
    for (int r = 0; r < 4; ++r)
#pragma unroll
        for (int c = 0; c < 8; ++c) acc[r][c] = 0.f;

    for (int kc = 0; kc < D; kc += 32) {
        // stage X tile (elu on the fly): each thread covers 8 consecutive k
        {
            int row = tid >> 2;
            int kq  = (tid & 3) * 8;
            int r = rowBase + row;
            float v[8];
            if (r < N) {
                if (isbf) {
                    const unsigned short* xb = (const unsigned short*)xv;
                    uint4 raw = *(const uint4*)(xb + (size_t)r * D + kc + kq);
                    unsigned int ws[4] = {raw.x, raw.y, raw.z, raw.w};
#pragma unroll
                    for (int i = 0; i < 4; ++i) {
                        v[2 * i]     = bf2f((unsigned short)(ws[i] & 0xffffu));
                        v[2 * i + 1] = bf2f((unsigned short)(ws[i] >> 16));
                    }
                } else {
                    const float* xf = (const float*)xv;
                    const float4* p4 = (const float4*)(xf + (size_t)r * D + kc + kq);
                    float4 f0 = p4[0], f1 = p4[1];
                    v[0] = f0.x; v[1] = f0.y; v[2] = f0.z; v[3] = f0.w;
                    v[4] = f1.x; v[5] = f1.y; v[6] = f1.z; v[7] = f1.w;
                }
#pragma unroll
                for (int i = 0; i < 8; ++i) v[i] = eluf(v[i]);
            } else {
#pragma unroll
                for (int i = 0; i < 8; ++i) v[i] = 0.f;
            }
#pragma unroll
            for (int i = 0; i < 8; ++i) xs[row][kq + i] = v[i];
        }
        // stage W tile: [Wsrc | Wdst] rows kc..kc+31, 8 values per thread x2
#pragma unroll
        for (int i = 0; i < 2; ++i) {
            int f = (tid + i * 256) * 8;
            int k = f >> 7;
            int c = f & 127;
            float v[8];
            if (isbf) {
                const unsigned short* Wp = (c < 64)
                    ? ((const unsigned short*)Wsrc + (size_t)(kc + k) * 64 + c)
                    : ((const unsigned short*)Wdst + (size_t)(kc + k) * 64 + (c - 64));
                uint4 raw = *(const uint4*)Wp;
                unsigned int ws[4] = {raw.x, raw.y, raw.z, raw.w};
#pragma unroll
                for (int q = 0; q < 4; ++q) {
                    v[2 * q]     = bf2f((unsigned short)(ws[q] & 0xffffu));
                    v[2 * q + 1] = bf2f((unsigned short)(ws[q] >> 16));
                }
            } else {
                const float* Wp = (c < 64)
                    ? ((const float*)Wsrc + (size_t)(kc + k) * 64 + c)
                    : ((const float*)Wdst + (size_t)(kc + k) * 64 + (c - 64));
                const float4* p4 = (const float4*)Wp;
                float4 f0 = p4[0], f1 = p4[1];
                v[0] = f0.x; v[1] = f0.y; v[2] = f0.z; v[3] = f0.w;
                v[4] = f1.x; v[5] = f1.y; v[6] = f1.z; v[7] = f1.w;
            }
#pragma unroll
            for (int q = 0; q < 8; ++q) wt[k][c + q] = v[q];
        }
        __syncthreads();
#pragma unroll 8
        for (int k = 0; k < 32; ++k) {
            float xr[4];
#pragma unroll
            for (int r = 0; r < 4; ++r) xr[r] = xs[tcy * 4 + r][k];
            float4 w0 = *(const float4*)&wt[k][tcx * 8];
            float4 w1 = *(const float4*)&wt[k][tcx * 8 + 4];
#pragma unroll
            for (int r = 0; r < 4; ++r) {
                acc[r][0] += xr[r] * w0.x; acc[r][1] += xr[r] * w0.y;
                acc[r][2] += xr[r] * w0.z; acc[r][3] += xr[r] * w0.w;
                acc[r][4] += xr[r] * w1.x; acc[r][5] += xr[r] * w1.y;
                acc[r][6] += xr[r] * w1.z; acc[r][7] += xr[r] * w1.w;
            }
        }
        __syncthreads();
    }
#pragma unroll
    for (int r = 0; r < 4; ++r) {
        int row = rowBase + tcy * 4 + r;
        if (row < N) {
            float* p = Pout + (size_t)row * 128 + tcx * 8;
            *(float4*)p       = make_float4(acc[r][0], acc[r][1], acc[r][2], acc[r][3]);
            *(float4*)(p + 4) = make_float4(acc[r][4], acc[r][5], acc[r][6], acc[r][7]);
        }
    }
}

// ---------- 2. per-node attention scalars ----------
__global__ __launch_bounds__(256) void a_proj_kernel(
    const float* __restrict__ P,
    const void* __restrict__ att_src, const void* __restrict__ att_dst,
    const int* __restrict__ flag,
    float* __restrict__ as_all, float* __restrict__ ad_all, int M)
{
    const int isbf = *flag;
    int wv = (blockIdx.x * 256 + threadIdx.x) >> 6;
    int lane = threadIdx.x & 63;
    if (wv >= M) return;
    float asv = isbf ? bf2f(((const unsigned short*)att_src)[lane])
                     : ((const float*)att_src)[lane];
    float adv = isbf ? bf2f(((const unsigned short*)att_dst)[lane])
                     : ((const float*)att_dst)[lane];
    const float* row = P + (size_t)wv * 128;
    float vs = row[lane]      * asv;
    float vd = row[64 + lane] * adv;
#pragma unroll
    for (int o = 16; o >= 1; o >>= 1) {   // reduce within each 32-lane head
        vs += __shfl_xor(vs, o, 64);
        vd += __shfl_xor(vd, o, 64);
    }
    if ((lane & 31) == 0) {
        int h = lane >> 5;
        as_all[(size_t)wv * 2 + h] = vs;
        ad_all[(size_t)wv * 2 + h] = vd;
    }
}

// ---------- 3a. degree histogram (dir1 by dst, dir2 by src) ----------
__global__ void count_kernel(const int* __restrict__ srce, const int* __restrict__ dste,
                             int* __restrict__ cnt, int N, int E)
{
    int e = blockIdx.x * blockDim.x + threadIdx.x;
    if (e >= E) return;
    atomicAdd(&cnt[dste[e]], 1);
    atomicAdd(&cnt[N + srce[e]], 1);
}

// ---------- 3b. single-block exclusive scan of cnt[0..M) -> off[0..M] ----------
__global__ __launch_bounds__(1024) void scan_kernel(const int* __restrict__ cnt,
                                                    int* __restrict__ off, int M)
{
    __shared__ int sums[1024];
    int t = threadIdx.x;
    int chunk = (M + 1023) >> 10;
    int b = t * chunk;
    int e = b + chunk; if (e > M) e = M;
    int s = 0;
    for (int i = b; i < e; ++i) s += cnt[i];
    sums[t] = s;
    __syncthreads();
    for (int o = 1; o < 1024; o <<= 1) {
        int v = (t >= o) ? sums[t - o] : 0;
        __syncthreads();
        sums[t] += v;
        __syncthreads();
    }
    int run = sums[t] - s;  // exclusive prefix
    for (int i = b; i < e; ++i) { off[i] = run; run += cnt[i]; }
    if (t == 1023) off[M] = sums[1023];
}

// ---------- 3c. CSR fill ----------
__global__ void fill_kernel(const int* __restrict__ srce, const int* __restrict__ dste,
                            const int* __restrict__ off, int* __restrict__ cur,
                            int* __restrict__ idx, int N, int E)
{
    int e = blockIdx.x * blockDim.x + threadIdx.x;
    if (e >= E) return;
    int s = srce[e], d = dste[e];
    int p  = atomicAdd(&cur[d], 1);
    idx[off[d] + p] = s;                 // dir1: node d receives from s
    int p2 = atomicAdd(&cur[N + s], 1);
    idx[off[N + s] + p2] = d;            // dir2: node s receives from d
}

// ---------- 4. enrichment softmax sums: S[0]=sum exp(c), S[1]=sum c*exp(c) ----------
__global__ void enrich_kernel(const void* __restrict__ ew, const int* __restrict__ flag,
                              float* __restrict__ S, int E)
{
    const int isbf = *flag;
    int i = blockIdx.x * blockDim.x + threadIdx.x;
    float e1 = 0.f, e2 = 0.f;
    if (i < E) {
        float c = isbf ? bf2f(((const unsigned short*)ew)[i]) : ((const float*)ew)[i];
        c = fminf(fmaxf(c, 0.3f), 3.0f);
        e1 = expf(c);
        e2 = c * e1;
    }
#pragma unroll
    for (int o = 32; o >= 1; o >>= 1) {
        e1 += __shfl_down(e1, o, 64);
        e2 += __shfl_down(e2, o, 64);
    }
    if ((threadIdx.x & 63) == 0) {
        atomicAdd(&S[0], e1);
        atomicAdd(&S[1], e2);
    }
}

// ---------- 5. per-dst-node online-softmax aggregation (one wave per node) ----------
__global__ __launch_bounds__(256) void agg_kernel(
    const int* __restrict__ off, const int* __restrict__ idx,
    const float* __restrict__ a_s, const float* __restrict__ a_d,
    const float* __restrict__ Psrc,
    const void* __restrict__ bias,
    const float* __restrict__ S,
    const void* __restrict__ esc,
    const int* __restrict__ flag,
    void* __restrict__ out, size_t outOff, int N, int dirBase)
{
    const int isbf = *flag;
    int n = (blockIdx.x * 256 + threadIdx.x) >> 6;
    int lane = threadIdx.x & 63;     // lane = h*32 + c
    if (n >= N) return;
    int h = lane >> 5;
    int g = dirBase + n;
    int jb = off[g], je = off[g + 1];
    float adv = a_d[(size_t)n * 2 + h];
    // self-loop initializes the online softmax (every node has one)
    float m = lrelu(a_s[(size_t)n * 2 + h] + adv);
    float z = 1.f;
    float acc = Psrc[(size_t)n * 128 + lane];
    for (int j = jb; j < je; ++j) {
        int sidx = idx[j];
        float alf = lrelu(a_s[(size_t)sidx * 2 + h] + adv);
        float msg = Psrc[(size_t)sidx * 128 + lane];
        if (alf <= m) {
            float p = expf(alf - m);
            z += p;
            acc += p * msg;
        } else {
            float sc = expf(m - alf);
            acc = acc * sc + msg;
            z   = z * sc + 1.f;
            m = alf;
        }
    }
    float escv = isbf ? bf2f(((const unsigned short*)esc)[0]) : ((const float*)esc)[0];
    float bv   = isbf ? bf2f(((const unsigned short*)bias)[lane]) : ((const float*)bias)[lane];
    float weighted = S[1] / S[0];
    float factor = 1.f + 0.5f * tanhf(escv) * (weighted - 1.f);
    float o = (acc / (z + 1e-16f) + bv) * factor;
    size_t oi = outOff + (size_t)n * 64 + lane;
    if (isbf) ((unsigned short*)out)[oi] = f2bf(o);
    else      ((float*)out)[oi] = o;
}

extern "C" void kernel_launch(void* const* d_in, const int* in_sizes, int n_in,
                              void* d_out, int out_size, void* d_ws, size_t ws_size,
                              hipStream_t stream)
{
    const void* hx      = d_in[0];
    const void* tx      = d_in[1];
    const int*  eidx    = (const int*)d_in[2];
    const void* ew      = d_in[3];
    const void* Wsrc    = d_in[4];
    const void* Wdst    = d_in[5];
    const void* att_src = d_in[6];
    const void* att_dst = d_in[7];
    const void* bias    = d_in[8];
    const void* esc     = d_in[9];

    const int HC = in_sizes[6];       // 64
    const int D  = in_sizes[4] / HC;  // 256
    const int N  = in_sizes[0] / D;   // 100000
    const int E  = in_sizes[3];       // 1600000
    const int* srce = eidx;
    const int* dste = eidx + E;

    char* wsb = (char*)d_ws;
    size_t o = 0;
    auto alloc = [&](size_t bytes) -> void* {
        void* p = wsb + o;
        o += (bytes + 255) & ~(size_t)255;
        return p;
    };
    float* Pall   = (float*)alloc((size_t)2 * N * 128 * 4);   // [Ph; Pt], f32
    float* as_all = (float*)alloc((size_t)2 * N * 2 * 4);
    float* ad_all = (float*)alloc((size_t)2 * N * 2 * 4);
    float* S      = (float*)alloc(2 * 4);
    int*   cnt    = (int*)alloc((size_t)2 * N * 4);
    int*   offp   = (int*)alloc(((size_t)2 * N + 1) * 4);
    int*   cur    = (int*)alloc((size_t)2 * N * 4);
    int*   idx    = (int*)alloc((size_t)2 * E * 4);
    int*   flag   = (int*)alloc(256);

    hipMemsetAsync(cnt, 0, (size_t)2 * N * 4, stream);
    hipMemsetAsync(cur, 0, (size_t)2 * N * 4, stream);
    hipMemsetAsync(S, 0, 2 * 4, stream);

    detect_kernel<<<1, 256, 0, stream>>>((const unsigned int*)hx, 65536, flag);

    dim3 gGemm((N + 63) / 64, 2);
    gemm_elu_kernel<<<gGemm, 256, 0, stream>>>(hx, tx, Wsrc, Wdst, flag, Pall, N, D);
    a_proj_kernel<<<(2 * N + 3) / 4, 256, 0, stream>>>(Pall, att_src, att_dst, flag,
                                                       as_all, ad_all, 2 * N);
    count_kernel<<<(E + 255) / 256, 256, 0, stream>>>(srce, dste, cnt, N, E);
    scan_kernel<<<1, 1024, 0, stream>>>(cnt, offp, 2 * N);
    fill_kernel<<<(E + 255) / 256, 256, 0, stream>>>(srce, dste, offp, cur, idx, N, E);
    enrich_kernel<<<(E + 255) / 256, 256, 0, stream>>>(ew, flag, S, E);

    // dir1 (h -> t): grouped by dst, messages = Ph, a_s=as_h, a_d=ad_t, out = t_rep
    agg_kernel<<<(N + 3) / 4, 256, 0, stream>>>(offp, idx,
                                                as_all, ad_all + (size_t)2 * N,
                                                Pall, bias, S, esc, flag,
                                                d_out, (size_t)N * 64, N, 0);
    // dir2 (t -> h): grouped by src, messages = Pt, a_s=as_t, a_d=ad_h, out = h_rep
    agg_kernel<<<(N + 3) / 4, 256, 0, stream>>>(offp, idx,
                                                as_all + (size_t)2 * N, ad_all,
                                                Pall + (size_t)N * 128, bias, S, esc, flag,
                                                d_out, 0, N, N);
}

// Round 3
// 1440.176 us; speedup vs baseline: 1.4393x; 1.4393x over previous
//
#include <hip/hip_runtime.h>
#include <math.h>

// ---------- bf16 helpers ----------
__device__ __forceinline__ float bf2f(unsigned short u) {
    union { unsigned int i; float f; } c;
    c.i = ((unsigned int)u) << 16;
    return c.f;
}
__device__ __forceinline__ unsigned short f2bf(float f) {
    union { float f; unsigned int i; } c;
    c.f = f;
    unsigned int b = c.i + 0x7FFFu + ((c.i >> 16) & 1u);  // round-nearest-even
    return (unsigned short)(b >> 16);
}
__device__ __forceinline__ float eluf(float v) {   // jax.nn.elu, alpha=1
    return v > 0.f ? v : (__expf(v) - 1.f);
}
__device__ __forceinline__ float lrelu(float v) {  // leaky_relu slope 0.2
    return v >= 0.f ? v : 0.2f * v;
}

// ---------- 0. input dtype detection: 1 = bf16, 0 = f32 ----------
__global__ void detect_kernel(const unsigned int* __restrict__ w, int nwords,
                              int* __restrict__ flag)
{
    __shared__ int cnt_s;
    if (threadIdx.x == 0) cnt_s = 0;
    __syncthreads();
    int sane = 0;
    for (int i = threadIdx.x; i < nwords; i += 256) {
        unsigned int lo = w[i] & 0xffffu;
        int e = (int)((lo >> 7) & 0xffu);
        if (e >= 114 && e <= 136) sane++;
    }
    atomicAdd(&cnt_s, sane);
    __syncthreads();
    if (threadIdx.x == 0) *flag = (2 * cnt_s > nwords) ? 1 : 0;
}

// ---------- 1. fused elu + GEMM: P[y] = elu(x_y) @ [Wsrc | Wdst]  ([N,128] f32) ----------
__global__ __launch_bounds__(256) void gemm_elu_kernel(
    const void* __restrict__ xh, const void* __restrict__ xt,
    const void* __restrict__ Wsrc, const void* __restrict__ Wdst,
    const int* __restrict__ flag,
    float* __restrict__ P, int N, int D)
{
    __shared__ float xs[64][33];    // 64 rows x 32 k, +1 pad
    __shared__ float wt[32][128];   // 32 k x 128 cols
    const int isbf = *flag;
    const void* xv = (blockIdx.y == 0) ? xh : xt;
    float* Pout = P + (size_t)blockIdx.y * (size_t)N * 128u;
    const int rowBase = blockIdx.x * 64;
    const int tid = threadIdx.x;
    const int tcx = tid & 15;   // col group: cols tcx*8 .. +7
    const int tcy = tid >> 4;   // row group: rows tcy*4 .. +3

    float acc[4][8];
#pragma unroll
    for (int r = 0; r < 4; ++r)
#pragma unroll
        for (int c = 0; c < 8; ++c) acc[r][c] = 0.f;

    for (int kc = 0; kc < D; kc += 32) {
        // stage X tile (elu on the fly): each thread covers 8 consecutive k
        {
            int row = tid >> 2;
            int kq  = (tid & 3) * 8;
            int r = rowBase + row;
            float v[8];
            if (r < N) {
                if (isbf) {
                    const unsigned short* xb = (const unsigned short*)xv;
                    uint4 raw = *(const uint4*)(xb + (size_t)r * D + kc + kq);
                    unsigned int ws[4] = {raw.x, raw.y, raw.z, raw.w};
#pragma unroll
                    for (int i = 0; i < 4; ++i) {
                        v[2 * i]     = bf2f((unsigned short)(ws[i] & 0xffffu));
                        v[2 * i + 1] = bf2f((unsigned short)(ws[i] >> 16));
                    }
                } else {
                    const float* xf = (const float*)xv;
                    const float4* p4 = (const float4*)(xf + (size_t)r * D + kc + kq);
                    float4 f0 = p4[0], f1 = p4[1];
                    v[0] = f0.x; v[1] = f0.y; v[2] = f0.z; v[3] = f0.w;
                    v[4] = f1.x; v[5] = f1.y; v[6] = f1.z; v[7] = f1.w;
                }
#pragma unroll
                for (int i = 0; i < 8; ++i) v[i] = eluf(v[i]);
            } else {
#pragma unroll
                for (int i = 0; i < 8; ++i) v[i] = 0.f;
            }
#pragma unroll
            for (int i = 0; i < 8; ++i) xs[row][kq + i] = v[i];
        }
        // stage W tile: [Wsrc | Wdst] rows kc..kc+31, 8 values per thread x2
#pragma unroll
        for (int i = 0; i < 2; ++i) {
            int f = (tid + i * 256) * 8;
            int k = f >> 7;
            int c = f & 127;
            float v[8];
            if (isbf) {
                const unsigned short* Wp = (c < 64)
                    ? ((const unsigned short*)Wsrc + (size_t)(kc + k) * 64 + c)
                    : ((const unsigned short*)Wdst + (size_t)(kc + k) * 64 + (c - 64));
                uint4 raw = *(const uint4*)Wp;
                unsigned int ws[4] = {raw.x, raw.y, raw.z, raw.w};
#pragma unroll
                for (int q = 0; q < 4; ++q) {
                    v[2 * q]     = bf2f((unsigned short)(ws[q] & 0xffffu));
                    v[2 * q + 1] = bf2f((unsigned short)(ws[q] >> 16));
                }
            } else {
                const float* Wp = (c < 64)
                    ? ((const float*)Wsrc + (size_t)(kc + k) * 64 + c)
                    : ((const float*)Wdst + (size_t)(kc + k) * 64 + (c - 64));
                const float4* p4 = (const float4*)Wp;
                float4 f0 = p4[0], f1 = p4[1];
                v[0] = f0.x; v[1] = f0.y; v[2] = f0.z; v[3] = f0.w;
                v[4] = f1.x; v[5] = f1.y; v[6] = f1.z; v[7] = f1.w;
            }
#pragma unroll
            for (int q = 0; q < 8; ++q) wt[k][c + q] = v[q];
        }
        __syncthreads();
#pragma unroll 8
        for (int k = 0; k < 32; ++k) {
            float xr[4];
#pragma unroll
            for (int r = 0; r < 4; ++r) xr[r] = xs[tcy * 4 + r][k];
            float4 w0 = *(const float4*)&wt[k][tcx * 8];
            float4 w1 = *(const float4*)&wt[k][tcx * 8 + 4];
#pragma unroll
            for (int r = 0; r < 4; ++r) {
                acc[r][0] += xr[r] * w0.x; acc[r][1] += xr[r] * w0.y;
                acc[r][2] += xr[r] * w0.z; acc[r][3] += xr[r] * w0.w;
                acc[r][4] += xr[r] * w1.x; acc[r][5] += xr[r] * w1.y;
                acc[r][6] += xr[r] * w1.z; acc[r][7] += xr[r] * w1.w;
            }
        }
        __syncthreads();
    }
#pragma unroll
    for (int r = 0; r < 4; ++r) {
        int row = rowBase + tcy * 4 + r;
        if (row < N) {
            float* p = Pout + (size_t)row * 128 + tcx * 8;
            *(float4*)p       = make_float4(acc[r][0], acc[r][1], acc[r][2], acc[r][3]);
            *(float4*)(p + 4) = make_float4(acc[r][4], acc[r][5], acc[r][6], acc[r][7]);
        }
    }
}

// ---------- 2. per-node attention scalars ----------
__global__ __launch_bounds__(256) void a_proj_kernel(
    const float* __restrict__ P,
    const void* __restrict__ att_src, const void* __restrict__ att_dst,
    const int* __restrict__ flag,
    float* __restrict__ as_all, float* __restrict__ ad_all, int M)
{
    const int isbf = *flag;
    int wv = (blockIdx.x * 256 + threadIdx.x) >> 6;
    int lane = threadIdx.x & 63;
    if (wv >= M) return;
    float asv = isbf ? bf2f(((const unsigned short*)att_src)[lane])
                     : ((const float*)att_src)[lane];
    float adv = isbf ? bf2f(((const unsigned short*)att_dst)[lane])
                     : ((const float*)att_dst)[lane];
    const float* row = P + (size_t)wv * 128;
    float vs = row[lane]      * asv;
    float vd = row[64 + lane] * adv;
#pragma unroll
    for (int o = 16; o >= 1; o >>= 1) {   // reduce within each 32-lane head
        vs += __shfl_xor(vs, o, 64);
        vd += __shfl_xor(vd, o, 64);
    }
    if ((lane & 31) == 0) {
        int h = lane >> 5;
        as_all[(size_t)wv * 2 + h] = vs;
        ad_all[(size_t)wv * 2 + h] = vd;
    }
}

// ---------- 3a. degree histogram (dir1 by dst, dir2 by src) ----------
__global__ void count_kernel(const int* __restrict__ srce, const int* __restrict__ dste,
                             int* __restrict__ cnt, int N, int E)
{
    int e = blockIdx.x * blockDim.x + threadIdx.x;
    if (e >= E) return;
    atomicAdd(&cnt[dste[e]], 1);
    atomicAdd(&cnt[N + srce[e]], 1);
}

// ---------- 3b. single-block exclusive scan of cnt[0..M) -> off[0..M] ----------
__global__ __launch_bounds__(1024) void scan_kernel(const int* __restrict__ cnt,
                                                    int* __restrict__ off, int M)
{
    __shared__ int sums[1024];
    int t = threadIdx.x;
    int chunk = (M + 1023) >> 10;
    int b = t * chunk;
    int e = b + chunk; if (e > M) e = M;
    int s = 0;
    for (int i = b; i < e; ++i) s += cnt[i];
    sums[t] = s;
    __syncthreads();
    for (int o = 1; o < 1024; o <<= 1) {
        int v = (t >= o) ? sums[t - o] : 0;
        __syncthreads();
        sums[t] += v;
        __syncthreads();
    }
    int run = sums[t] - s;  // exclusive prefix
    for (int i = b; i < e; ++i) { off[i] = run; run += cnt[i]; }
    if (t == 1023) off[M] = sums[1023];
}

// ---------- 3c. CSR fill ----------
__global__ void fill_kernel(const int* __restrict__ srce, const int* __restrict__ dste,
                            const int* __restrict__ off, int* __restrict__ cur,
                            int* __restrict__ idx, int N, int E)
{
    int e = blockIdx.x * blockDim.x + threadIdx.x;
    if (e >= E) return;
    int s = srce[e], d = dste[e];
    int p  = atomicAdd(&cur[d], 1);
    idx[off[d] + p] = s;                 // dir1: node d receives from s
    int p2 = atomicAdd(&cur[N + s], 1);
    idx[off[N + s] + p2] = d;            // dir2: node s receives from d
}

// ---------- 4. enrichment softmax sums: S[0]=sum exp(c), S[1]=sum c*exp(c) ----------
// Grid-stride + LDS block reduction: 2 atomics per BLOCK (was per wave -> 636us).
__global__ __launch_bounds__(256) void enrich_kernel(
    const void* __restrict__ ew, const int* __restrict__ flag,
    float* __restrict__ S, int E)
{
    __shared__ float r1[4], r2[4];
    const int isbf = *flag;
    float e1 = 0.f, e2 = 0.f;
    for (int i = blockIdx.x * 256 + threadIdx.x; i < E; i += gridDim.x * 256) {
        float c = isbf ? bf2f(((const unsigned short*)ew)[i]) : ((const float*)ew)[i];
        c = fminf(fmaxf(c, 0.3f), 3.0f);
        float ex = __expf(c);
        e1 += ex;
        e2 += c * ex;
    }
#pragma unroll
    for (int o = 32; o >= 1; o >>= 1) {
        e1 += __shfl_down(e1, o, 64);
        e2 += __shfl_down(e2, o, 64);
    }
    int lane = threadIdx.x & 63;
    int wv = threadIdx.x >> 6;
    if (lane == 0) { r1[wv] = e1; r2[wv] = e2; }
    __syncthreads();
    if (threadIdx.x == 0) {
        float s1 = r1[0] + r1[1] + r1[2] + r1[3];
        float s2 = r2[0] + r2[1] + r2[2] + r2[3];
        atomicAdd(&S[0], s1);
        atomicAdd(&S[1], s2);
    }
}

// ---------- 5. per-dst-node online-softmax aggregation (one wave per node) ----------
__global__ __launch_bounds__(256) void agg_kernel(
    const int* __restrict__ off, const int* __restrict__ idx,
    const float* __restrict__ a_s, const float* __restrict__ a_d,
    const float* __restrict__ Psrc,
    const void* __restrict__ bias,
    const float* __restrict__ S,
    const void* __restrict__ esc,
    const int* __restrict__ flag,
    void* __restrict__ out, size_t outOff, int N, int dirBase)
{
    const int isbf = *flag;
    int n = (blockIdx.x * 256 + threadIdx.x) >> 6;
    int lane = threadIdx.x & 63;     // lane = h*32 + c
    if (n >= N) return;
    int h = lane >> 5;
    int g = dirBase + n;
    int jb = off[g], je = off[g + 1];
    float adv = a_d[(size_t)n * 2 + h];
    // self-loop initializes the online softmax (every node has one)
    float m = lrelu(a_s[(size_t)n * 2 + h] + adv);
    float z = 1.f;
    float acc = Psrc[(size_t)n * 128 + lane];
    for (int j = jb; j < je; ++j) {
        int sidx = idx[j];
        float alf = lrelu(a_s[(size_t)sidx * 2 + h] + adv);
        float msg = Psrc[(size_t)sidx * 128 + lane];
        if (alf <= m) {
            float p = __expf(alf - m);
            z += p;
            acc += p * msg;
        } else {
            float sc = __expf(m - alf);
            acc = acc * sc + msg;
            z   = z * sc + 1.f;
            m = alf;
        }
    }
    float escv = isbf ? bf2f(((const unsigned short*)esc)[0]) : ((const float*)esc)[0];
    float bv   = isbf ? bf2f(((const unsigned short*)bias)[lane]) : ((const float*)bias)[lane];
    float weighted = S[1] / S[0];
    float factor = 1.f + 0.5f * tanhf(escv) * (weighted - 1.f);
    float o = (acc / (z + 1e-16f) + bv) * factor;
    size_t oi = outOff + (size_t)n * 64 + lane;
    if (isbf) ((unsigned short*)out)[oi] = f2bf(o);
    else      ((float*)out)[oi] = o;
}

extern "C" void kernel_launch(void* const* d_in, const int* in_sizes, int n_in,
                              void* d_out, int out_size, void* d_ws, size_t ws_size,
                              hipStream_t stream)
{
    const void* hx      = d_in[0];
    const void* tx      = d_in[1];
    const int*  eidx    = (const int*)d_in[2];
    const void* ew      = d_in[3];
    const void* Wsrc    = d_in[4];
    const void* Wdst    = d_in[5];
    const void* att_src = d_in[6];
    const void* att_dst = d_in[7];
    const void* bias    = d_in[8];
    const void* esc     = d_in[9];

    const int HC = in_sizes[6];       // 64
    const int D  = in_sizes[4] / HC;  // 256
    const int N  = in_sizes[0] / D;   // 100000
    const int E  = in_sizes[3];       // 1600000
    const int* srce = eidx;
    const int* dste = eidx + E;

    char* wsb = (char*)d_ws;
    size_t o = 0;
    auto alloc = [&](size_t bytes) -> void* {
        void* p = wsb + o;
        o += (bytes + 255) & ~(size_t)255;
        return p;
    };
    float* Pall   = (float*)alloc((size_t)2 * N * 128 * 4);   // [Ph; Pt], f32
    float* as_all = (float*)alloc((size_t)2 * N * 2 * 4);
    float* ad_all = (float*)alloc((size_t)2 * N * 2 * 4);
    float* S      = (float*)alloc(2 * 4);
    int*   cnt    = (int*)alloc((size_t)2 * N * 4);
    int*   offp   = (int*)alloc(((size_t)2 * N + 1) * 4);
    int*   cur    = (int*)alloc((size_t)2 * N * 4);
    int*   idx    = (int*)alloc((size_t)2 * E * 4);
    int*   flag   = (int*)alloc(256);

    hipMemsetAsync(cnt, 0, (size_t)2 * N * 4, stream);
    hipMemsetAsync(cur, 0, (size_t)2 * N * 4, stream);
    hipMemsetAsync(S, 0, 2 * 4, stream);

    detect_kernel<<<1, 256, 0, stream>>>((const unsigned int*)hx, 65536, flag);

    dim3 gGemm((N + 63) / 64, 2);
    gemm_elu_kernel<<<gGemm, 256, 0, stream>>>(hx, tx, Wsrc, Wdst, flag, Pall, N, D);
    a_proj_kernel<<<(2 * N + 3) / 4, 256, 0, stream>>>(Pall, att_src, att_dst, flag,
                                                       as_all, ad_all, 2 * N);
    count_kernel<<<(E + 255) / 256, 256, 0, stream>>>(srce, dste, cnt, N, E);
    scan_kernel<<<1, 1024, 0, stream>>>(cnt, offp, 2 * N);
    fill_kernel<<<(E + 255) / 256, 256, 0, stream>>>(srce, dste, offp, cur, idx, N, E);
    enrich_kernel<<<512, 256, 0, stream>>>(ew, flag, S, E);

    // dir1 (h -> t): grouped by dst, messages = Ph, a_s=as_h, a_d=ad_t, out = t_rep
    agg_kernel<<<(N + 3) / 4, 256, 0, stream>>>(offp, idx,
                                                as_all, ad_all + (size_t)2 * N,
                                                Pall, bias, S, esc, flag,
                                                d_out, (size_t)N * 64, N, 0);
    // dir2 (t -> h): grouped by src, messages = Pt, a_s=as_t, a_d=ad_h, out = h_rep
    agg_kernel<<<(N + 3) / 4, 256, 0, stream>>>(offp, idx,
                                                as_all + (size_t)2 * N, ad_all,
                                                Pall + (size_t)N * 128, bias, S, esc, flag,
                                                d_out, 0, N, N);
}

// Round 4
// 1129.386 us; speedup vs baseline: 1.8354x; 1.2752x over previous
//
#include <hip/hip_runtime.h>
#include <math.h>

// ---------- bf16 helpers ----------
__device__ __forceinline__ float bf2f(unsigned short u) {
    union { unsigned int i; float f; } c;
    c.i = ((unsigned int)u) << 16;
    return c.f;
}
__device__ __forceinline__ unsigned short f2bf(float f) {
    union { float f; unsigned int i; } c;
    c.f = f;
    unsigned int b = c.i + 0x7FFFu + ((c.i >> 16) & 1u);  // round-nearest-even
    return (unsigned short)(b >> 16);
}
__device__ __forceinline__ float eluf(float v) {   // jax.nn.elu, alpha=1
    return v > 0.f ? v : (__expf(v) - 1.f);
}
__device__ __forceinline__ float lrelu(float v) {  // leaky_relu slope 0.2
    return v >= 0.f ? v : 0.2f * v;
}

// ---------- 0. input dtype detection: 1 = bf16, 0 = f32 ----------
__global__ void detect_kernel(const unsigned int* __restrict__ w, int nwords,
                              int* __restrict__ flag)
{
    __shared__ int cnt_s;
    if (threadIdx.x == 0) cnt_s = 0;
    __syncthreads();
    int sane = 0;
    for (int i = threadIdx.x; i < nwords; i += 256) {
        unsigned int lo = w[i] & 0xffffu;
        int e = (int)((lo >> 7) & 0xffu);
        if (e >= 114 && e <= 136) sane++;
    }
    atomicAdd(&cnt_s, sane);
    __syncthreads();
    if (threadIdx.x == 0) *flag = (2 * cnt_s > nwords) ? 1 : 0;
}

// ---------- 1. fused elu + GEMM: P[y] = elu(x_y) @ [Wsrc | Wdst]  ([N,128] f32) ----------
__global__ __launch_bounds__(256) void gemm_elu_kernel(
    const void* __restrict__ xh, const void* __restrict__ xt,
    const void* __restrict__ Wsrc, const void* __restrict__ Wdst,
    const int* __restrict__ flag,
    float* __restrict__ P, int N, int D)
{
    __shared__ float xs[64][33];    // 64 rows x 32 k, +1 pad
    __shared__ float wt[32][128];   // 32 k x 128 cols
    const int isbf = *flag;
    const void* xv = (blockIdx.y == 0) ? xh : xt;
    float* Pout = P + (size_t)blockIdx.y * (size_t)N * 128u;
    const int rowBase = blockIdx.x * 64;
    const int tid = threadIdx.x;
    const int tcx = tid & 15;   // col group: cols tcx*8 .. +7
    const int tcy = tid >> 4;   // row group: rows tcy*4 .. +3

    float acc[4][8];
#pragma unroll
    for (int r = 0; r < 4; ++r)
#pragma unroll
        for (int c = 0; c < 8; ++c) acc[r][c] = 0.f;

    for (int kc = 0; kc < D; kc += 32) {
        // stage X tile (elu on the fly): each thread covers 8 consecutive k
        {
            int row = tid >> 2;
            int kq  = (tid & 3) * 8;
            int r = rowBase + row;
            float v[8];
            if (r < N) {
                if (isbf) {
                    const unsigned short* xb = (const unsigned short*)xv;
                    uint4 raw = *(const uint4*)(xb + (size_t)r * D + kc + kq);
                    unsigned int ws[4] = {raw.x, raw.y, raw.z, raw.w};
#pragma unroll
                    for (int i = 0; i < 4; ++i) {
                        v[2 * i]     = bf2f((unsigned short)(ws[i] & 0xffffu));
                        v[2 * i + 1] = bf2f((unsigned short)(ws[i] >> 16));
                    }
                } else {
                    const float* xf = (const float*)xv;
                    const float4* p4 = (const float4*)(xf + (size_t)r * D + kc + kq);
                    float4 f0 = p4[0], f1 = p4[1];
                    v[0] = f0.x; v[1] = f0.y; v[2] = f0.z; v[3] = f0.w;
                    v[4] = f1.x; v[5] = f1.y; v[6] = f1.z; v[7] = f1.w;
                }
#pragma unroll
                for (int i = 0; i < 8; ++i) v[i] = eluf(v[i]);
            } else {
#pragma unroll
                for (int i = 0; i < 8; ++i) v[i] = 0.f;
            }
#pragma unroll
            for (int i = 0; i < 8; ++i) xs[row][kq + i] = v[i];
        }
        // stage W tile: [Wsrc | Wdst] rows kc..kc+31, 8 values per thread x2
#pragma unroll
        for (int i = 0; i < 2; ++i) {
            int f = (tid + i * 256) * 8;
            int k = f >> 7;
            int c = f & 127;
            float v[8];
            if (isbf) {
                const unsigned short* Wp = (c < 64)
                    ? ((const unsigned short*)Wsrc + (size_t)(kc + k) * 64 + c)
                    : ((const unsigned short*)Wdst + (size_t)(kc + k) * 64 + (c - 64));
                uint4 raw = *(const uint4*)Wp;
                unsigned int ws[4] = {raw.x, raw.y, raw.z, raw.w};
#pragma unroll
                for (int q = 0; q < 4; ++q) {
                    v[2 * q]     = bf2f((unsigned short)(ws[q] & 0xffffu));
                    v[2 * q + 1] = bf2f((unsigned short)(ws[q] >> 16));
                }
            } else {
                const float* Wp = (c < 64)
                    ? ((const float*)Wsrc + (size_t)(kc + k) * 64 + c)
                    : ((const float*)Wdst + (size_t)(kc + k) * 64 + (c - 64));
                const float4* p4 = (const float4*)Wp;
                float4 f0 = p4[0], f1 = p4[1];
                v[0] = f0.x; v[1] = f0.y; v[2] = f0.z; v[3] = f0.w;
                v[4] = f1.x; v[5] = f1.y; v[6] = f1.z; v[7] = f1.w;
            }
#pragma unroll
            for (int q = 0; q < 8; ++q) wt[k][c + q] = v[q];
        }
        __syncthreads();
#pragma unroll 8
        for (int k = 0; k < 32; ++k) {
            float xr[4];
#pragma unroll
            for (int r = 0; r < 4; ++r) xr[r] = xs[tcy * 4 + r][k];
            float4 w0 = *(const float4*)&wt[k][tcx * 8];
            float4 w1 = *(const float4*)&wt[k][tcx * 8 + 4];
#pragma unroll
            for (int r = 0; r < 4; ++r) {
                acc[r][0] += xr[r] * w0.x; acc[r][1] += xr[r] * w0.y;
                acc[r][2] += xr[r] * w0.z; acc[r][3] += xr[r] * w0.w;
                acc[r][4] += xr[r] * w1.x; acc[r][5] += xr[r] * w1.y;
                acc[r][6] += xr[r] * w1.z; acc[r][7] += xr[r] * w1.w;
            }
        }
        __syncthreads();
    }
#pragma unroll
    for (int r = 0; r < 4; ++r) {
        int row = rowBase + tcy * 4 + r;
        if (row < N) {
            float* p = Pout + (size_t)row * 128 + tcx * 8;
            *(float4*)p       = make_float4(acc[r][0], acc[r][1], acc[r][2], acc[r][3]);
            *(float4*)(p + 4) = make_float4(acc[r][4], acc[r][5], acc[r][6], acc[r][7]);
        }
    }
}

// ---------- 2. per-node attention scalars ----------
__global__ __launch_bounds__(256) void a_proj_kernel(
    const float* __restrict__ P,
    const void* __restrict__ att_src, const void* __restrict__ att_dst,
    const int* __restrict__ flag,
    float* __restrict__ as_all, float* __restrict__ ad_all, int M)
{
    const int isbf = *flag;
    int wv = (blockIdx.x * 256 + threadIdx.x) >> 6;
    int lane = threadIdx.x & 63;
    if (wv >= M) return;
    float asv = isbf ? bf2f(((const unsigned short*)att_src)[lane])
                     : ((const float*)att_src)[lane];
    float adv = isbf ? bf2f(((const unsigned short*)att_dst)[lane])
                     : ((const float*)att_dst)[lane];
    const float* row = P + (size_t)wv * 128;
    float vs = row[lane]      * asv;
    float vd = row[64 + lane] * adv;
#pragma unroll
    for (int o = 16; o >= 1; o >>= 1) {   // reduce within each 32-lane head
        vs += __shfl_xor(vs, o, 64);
        vd += __shfl_xor(vd, o, 64);
    }
    if ((lane & 31) == 0) {
        int h = lane >> 5;
        as_all[(size_t)wv * 2 + h] = vs;
        ad_all[(size_t)wv * 2 + h] = vd;
    }
}

// ---------- 3a. degree histogram (dir1 by dst, dir2 by src) ----------
__global__ void count_kernel(const int* __restrict__ srce, const int* __restrict__ dste,
                             int* __restrict__ cnt, int N, int E)
{
    int e = blockIdx.x * blockDim.x + threadIdx.x;
    if (e >= E) return;
    atomicAdd(&cnt[dste[e]], 1);
    atomicAdd(&cnt[N + srce[e]], 1);
}

// ---------- 3b. multi-block scan: stage 1 — coalesced per-block sums ----------
__global__ __launch_bounds__(256) void scan_bsum_kernel(
    const int* __restrict__ cnt, int M, int chunk, int* __restrict__ bsum)
{
    __shared__ int r[4];
    int beg = blockIdx.x * chunk;
    int end = beg + chunk; if (end > M) end = M;
    int s = 0;
    for (int i = beg + threadIdx.x; i < end; i += 256) s += cnt[i];
#pragma unroll
    for (int o = 32; o >= 1; o >>= 1) s += __shfl_down(s, o, 64);
    int lane = threadIdx.x & 63, wv = threadIdx.x >> 6;
    if (lane == 0) r[wv] = s;
    __syncthreads();
    if (threadIdx.x == 0) bsum[blockIdx.x] = r[0] + r[1] + r[2] + r[3];
}

// ---------- stage 2: exclusive scan of block sums (NB <= 256), 1 block ----------
__global__ __launch_bounds__(256) void scan_boff_kernel(
    const int* __restrict__ bsum, int NB, int* __restrict__ boff)
{
    __shared__ int s[256];
    int t = threadIdx.x;
    int v = (t < NB) ? bsum[t] : 0;
    s[t] = v;
    __syncthreads();
    for (int o = 1; o < 256; o <<= 1) {
        int x = (t >= o) ? s[t - o] : 0;
        __syncthreads();
        s[t] += x;
        __syncthreads();
    }
    if (t < NB) boff[t] = s[t] - v;   // exclusive
}

// ---------- stage 3: per-block coalesced tile scan + prefix, write off[] ----------
__global__ __launch_bounds__(256) void scan_write_kernel(
    const int* __restrict__ cnt, int M, int chunk,
    const int* __restrict__ boff, int* __restrict__ off)
{
    __shared__ int s[256];
    int t = threadIdx.x;
    int beg = blockIdx.x * chunk;
    int end = beg + chunk; if (end > M) end = M;
    if (beg >= M) return;
    int running = boff[blockIdx.x];
    for (int base = beg; base < end; base += 256) {
        int i = base + t;
        int v = (i < end) ? cnt[i] : 0;
        s[t] = v;
        __syncthreads();
        for (int o = 1; o < 256; o <<= 1) {
            int x = (t >= o) ? s[t - o] : 0;
            __syncthreads();
            s[t] += x;
            __syncthreads();
        }
        if (i < end) off[i] = running + s[t] - v;  // exclusive
        int total = s[255];
        __syncthreads();   // everyone has read s[255] before next tile overwrites
        running += total;
    }
    if (end == M && t == 0) off[M] = running;
}

// ---------- 3c. CSR fill ----------
__global__ void fill_kernel(const int* __restrict__ srce, const int* __restrict__ dste,
                            const int* __restrict__ off, int* __restrict__ cur,
                            int* __restrict__ idx, int N, int E)
{
    int e = blockIdx.x * blockDim.x + threadIdx.x;
    if (e >= E) return;
    int s = srce[e], d = dste[e];
    int p  = atomicAdd(&cur[d], 1);
    idx[off[d] + p] = s;                 // dir1: node d receives from s
    int p2 = atomicAdd(&cur[N + s], 1);
    idx[off[N + s] + p2] = d;            // dir2: node s receives from d
}

// ---------- 4. enrichment softmax sums: S[0]=sum exp(c), S[1]=sum c*exp(c) ----------
__global__ __launch_bounds__(256) void enrich_kernel(
    const void* __restrict__ ew, const int* __restrict__ flag,
    float* __restrict__ S, int E)
{
    __shared__ float r1[4], r2[4];
    const int isbf = *flag;
    float e1 = 0.f, e2 = 0.f;
    for (int i = blockIdx.x * 256 + threadIdx.x; i < E; i += gridDim.x * 256) {
        float c = isbf ? bf2f(((const unsigned short*)ew)[i]) : ((const float*)ew)[i];
        c = fminf(fmaxf(c, 0.3f), 3.0f);
        float ex = __expf(c);
        e1 += ex;
        e2 += c * ex;
    }
#pragma unroll
    for (int o = 32; o >= 1; o >>= 1) {
        e1 += __shfl_down(e1, o, 64);
        e2 += __shfl_down(e2, o, 64);
    }
    int lane = threadIdx.x & 63;
    int wv = threadIdx.x >> 6;
    if (lane == 0) { r1[wv] = e1; r2[wv] = e2; }
    __syncthreads();
    if (threadIdx.x == 0) {
        atomicAdd(&S[0], r1[0] + r1[1] + r1[2] + r1[3]);
        atomicAdd(&S[1], r2[0] + r2[1] + r2[2] + r2[3]);
    }
}

// ---------- 5. per-dst-node online-softmax aggregation (one wave per node) ----------
__global__ __launch_bounds__(256) void agg_kernel(
    const int* __restrict__ off, const int* __restrict__ idx,
    const float* __restrict__ a_s, const float* __restrict__ a_d,
    const float* __restrict__ Psrc,
    const void* __restrict__ bias,
    const float* __restrict__ S,
    const void* __restrict__ esc,
    const int* __restrict__ flag,
    void* __restrict__ out, size_t outOff, int N, int dirBase)
{
    const int isbf = *flag;
    int n = (blockIdx.x * 256 + threadIdx.x) >> 6;
    int lane = threadIdx.x & 63;     // lane = h*32 + c
    if (n >= N) return;
    int h = lane >> 5;
    int g = dirBase + n;
    int jb = off[g], je = off[g + 1];
    float adv = a_d[(size_t)n * 2 + h];
    // self-loop initializes the online softmax (every node has one)
    float m = lrelu(a_s[(size_t)n * 2 + h] + adv);
    float z = 1.f;
    float acc = Psrc[(size_t)n * 128 + lane];
    for (int j = jb; j < je; ++j) {
        int sidx = idx[j];
        float alf = lrelu(a_s[(size_t)sidx * 2 + h] + adv);
        float msg = Psrc[(size_t)sidx * 128 + lane];
        if (alf <= m) {
            float p = __expf(alf - m);
            z += p;
            acc += p * msg;
        } else {
            float sc = __expf(m - alf);
            acc = acc * sc + msg;
            z   = z * sc + 1.f;
            m = alf;
        }
    }
    float escv = isbf ? bf2f(((const unsigned short*)esc)[0]) : ((const float*)esc)[0];
    float bv   = isbf ? bf2f(((const unsigned short*)bias)[lane]) : ((const float*)bias)[lane];
    float weighted = S[1] / S[0];
    float factor = 1.f + 0.5f * tanhf(escv) * (weighted - 1.f);
    float o = (acc / (z + 1e-16f) + bv) * factor;
    size_t oi = outOff + (size_t)n * 64 + lane;
    if (isbf) ((unsigned short*)out)[oi] = f2bf(o);
    else      ((float*)out)[oi] = o;
}

extern "C" void kernel_launch(void* const* d_in, const int* in_sizes, int n_in,
                              void* d_out, int out_size, void* d_ws, size_t ws_size,
                              hipStream_t stream)
{
    const void* hx      = d_in[0];
    const void* tx      = d_in[1];
    const int*  eidx    = (const int*)d_in[2];
    const void* ew      = d_in[3];
    const void* Wsrc    = d_in[4];
    const void* Wdst    = d_in[5];
    const void* att_src = d_in[6];
    const void* att_dst = d_in[7];
    const void* bias    = d_in[8];
    const void* esc     = d_in[9];

    const int HC = in_sizes[6];       // 64
    const int D  = in_sizes[4] / HC;  // 256
    const int N  = in_sizes[0] / D;   // 100000
    const int E  = in_sizes[3];       // 1600000
    const int* srce = eidx;
    const int* dste = eidx + E;

    char* wsb = (char*)d_ws;
    size_t o = 0;
    auto alloc = [&](size_t bytes) -> void* {
        void* p = wsb + o;
        o += (bytes + 255) & ~(size_t)255;
        return p;
    };
    float* Pall   = (float*)alloc((size_t)2 * N * 128 * 4);   // [Ph; Pt], f32
    float* as_all = (float*)alloc((size_t)2 * N * 2 * 4);
    float* ad_all = (float*)alloc((size_t)2 * N * 2 * 4);
    float* S      = (float*)alloc(2 * 4);
    int*   cnt    = (int*)alloc((size_t)2 * N * 4);
    int*   offp   = (int*)alloc(((size_t)2 * N + 1) * 4);
    int*   cur    = (int*)alloc((size_t)2 * N * 4);
    int*   idx    = (int*)alloc((size_t)2 * E * 4);
    int*   flag   = (int*)alloc(256);
    int*   bsum   = (int*)alloc(256 * 4);
    int*   boff   = (int*)alloc(256 * 4);

    hipMemsetAsync(cnt, 0, (size_t)2 * N * 4, stream);
    hipMemsetAsync(cur, 0, (size_t)2 * N * 4, stream);
    hipMemsetAsync(S, 0, 2 * 4, stream);

    detect_kernel<<<1, 256, 0, stream>>>((const unsigned int*)hx, 65536, flag);

    dim3 gGemm((N + 63) / 64, 2);
    gemm_elu_kernel<<<gGemm, 256, 0, stream>>>(hx, tx, Wsrc, Wdst, flag, Pall, N, D);
    a_proj_kernel<<<(2 * N + 3) / 4, 256, 0, stream>>>(Pall, att_src, att_dst, flag,
                                                       as_all, ad_all, 2 * N);
    count_kernel<<<(E + 255) / 256, 256, 0, stream>>>(srce, dste, cnt, N, E);

    // multi-block coalesced scan of cnt[0..2N) -> offp[0..2N]
    const int M = 2 * N;
    int chunk = (M + 255) / 256;           // per-block elements, then round to 256
    chunk = (chunk + 255) & ~255;
    const int NB = (M + chunk - 1) / chunk;  // <= 256
    scan_bsum_kernel<<<NB, 256, 0, stream>>>(cnt, M, chunk, bsum);
    scan_boff_kernel<<<1, 256, 0, stream>>>(bsum, NB, boff);
    scan_write_kernel<<<NB, 256, 0, stream>>>(cnt, M, chunk, boff, offp);

    fill_kernel<<<(E + 255) / 256, 256, 0, stream>>>(srce, dste, offp, cur, idx, N, E);
    enrich_kernel<<<512, 256, 0, stream>>>(ew, flag, S, E);

    // dir1 (h -> t): grouped by dst, messages = Ph, a_s=as_h, a_d=ad_t, out = t_rep
    agg_kernel<<<(N + 3) / 4, 256, 0, stream>>>(offp, idx,
                                                as_all, ad_all + (size_t)2 * N,
                                                Pall, bias, S, esc, flag,
                                                d_out, (size_t)N * 64, N, 0);
    // dir2 (t -> h): grouped by src, messages = Pt, a_s=as_t, a_d=ad_h, out = h_rep
    agg_kernel<<<(N + 3) / 4, 256, 0, stream>>>(offp, idx,
                                                as_all + (size_t)2 * N, ad_all,
                                                Pall + (size_t)N * 128, bias, S, esc, flag,
                                                d_out, 0, N, N);
}